// Round 4
// baseline (189.129 us; speedup 1.0000x reference)
//
#include <hip/hip_runtime.h>

#define T_ 12
#define N_ 1370
#define MSEQ 32        // sequences per block
#define LDA 88         // hbuf row stride in shorts (176B): 2-way banks on b128
#define HBUF (MSEQ * LDA)
#define NBLK 2740      // 87680 / 32

typedef __attribute__((ext_vector_type(8))) short short8;
typedef __attribute__((ext_vector_type(4))) float floatx4;

#define NLOG2E -1.4426950408889634f
#define TLOG2E 2.8853900817779268f

__device__ __forceinline__ short f2bf(float x) {
  unsigned u = __builtin_bit_cast(unsigned, x);
  u = (u + 0x7fffu + ((u >> 16) & 1u)) >> 16;
  return (short)u;
}
__device__ __forceinline__ unsigned pk_bf16(float a, float b) {
  unsigned r;
  asm("v_cvt_pk_bf16_f32 %0, %1, %2" : "=v"(r) : "v"(a), "v"(b));
  return r;
}
__device__ __forceinline__ short8 load_w8s(const float* __restrict__ p, float s) {
  short8 r;
#pragma unroll
  for (int j = 0; j < 8; ++j) r[j] = f2bf(p[j] * s);
  return r;
}

// Block = 32 seqs, 4 waves, swapped-operand MFMA: A = weights (m = gate row),
// B = hbuf row [h(0..63) | x_t(64..71) | 1.0(72) | pad(73..87)] (n = seq).
// K chunks 0..31 / 32..63 / 64..95: chunk2 A rows: q=0 -> W_ih (k=64..71),
// q=1 j=0 -> scaled bias (k=72), all other rows ZERO -> B values there
// (pads, next-row overrun for q=3) are multiplied by zero = harmless.
// x is held in registers (12 bf16 packed in 6 VGPRs per thread) and dropped
// into the write-buffer's x columns each step (one ds_write_b16).
// D layout: col=lane&15 = seq, row=q*4+r = unit -> i/f/g/o of a cell share
// reg index r; c stays fp32 in registers; h writeback = one ds_write_b64.
// Activation scaling pre-folded into weights/bias: i,f,o rows by -log2e
// (sigma = 1/(1+2^y)), g rows by 2*log2e (tanh = 1 - 2/(1+2^y)); one v_rcp
// serves all 4 gate denominators (product < 2^128 for |preact| < ~22).
__global__ void __launch_bounds__(256, 5) lstm_kernel(
    const float* __restrict__ x, const float* __restrict__ W_ih,
    const float* __restrict__ W_hh, const float* __restrict__ b_ih,
    const float* __restrict__ b_hh, const float* __restrict__ W_fc,
    const float* __restrict__ b_fc, float* __restrict__ out) {
  __shared__ short hbuf[2 * HBUF + 8];  // +8: q=3 chunk2 overrun pad

  const int tid = threadIdx.x;
  const int wave = tid >> 6;
  const int lane = tid & 63;
  const int m16 = lane & 15;
  const int q = lane >> 4;
  const int blk = blockIdx.x;

  // ---- x -> registers: thread (xseq, xc) holds x[xseq][t][xc], t=0..11 ----
  const int xseq = tid >> 3, xc = tid & 7;
  unsigned xpk[6];
  {
    const int s0 = blk * MSEQ + xseq;
    const int bidx = s0 / N_;
    const int nidx = s0 - bidx * N_;
    const float* xp = x + ((size_t)(bidx * T_) * N_ + nidx) * 8 + xc;
    float xv[T_];
#pragma unroll
    for (int t = 0; t < T_; ++t) xv[t] = xp[(size_t)t * (N_ * 8)];
#pragma unroll
    for (int i = 0; i < 6; ++i) xpk[i] = pk_bf16(xv[2 * i], xv[2 * i + 1]);
  }

  // ---- A-operand weight fragments: lane row = gate unit wave*16+m16 ----
  const int urow = wave * 16 + m16;
  short8 wA[4][3];
#pragma unroll
  for (int g = 0; g < 4; ++g) {
    const float sg = (g == 2) ? TLOG2E : NLOG2E;
    const int grow = g * 64 + urow;
    const float* wr = W_hh + grow * 64;
    wA[g][0] = load_w8s(wr + q * 8, sg);
    wA[g][1] = load_w8s(wr + 32 + q * 8, sg);
    short8 z = {0, 0, 0, 0, 0, 0, 0, 0};
    if (q == 0) {
      wA[g][2] = load_w8s(W_ih + grow * 8, sg);      // k = 64..71: x cols
    } else if (q == 1) {
      z[0] = f2bf(sg * (b_ih[grow] + b_hh[grow]));   // k = 72: bias col
      wA[g][2] = z;
    } else {
      wA[g][2] = z;                                  // k = 80..95 dead
    }
  }

  // ---- zero LDS (h0 = 0), then bias columns + x_0 ----
  {
    int* hp = (int*)hbuf;
#pragma unroll
    for (int i = tid; i < (2 * HBUF + 8) / 2; i += 256) hp[i] = 0;
  }
  __syncthreads();
  if (tid < 2 * MSEQ)
    hbuf[(tid >> 5) * HBUF + (tid & 31) * LDA + 72] = (short)0x3F80;  // 1.0
  hbuf[xseq * LDA + 64 + xc] = (short)xpk[0];  // x_0 into buffer 0
  __syncthreads();

  const floatx4 zacc = {0.0f, 0.0f, 0.0f, 0.0f};
  float cst[2][4];
#pragma unroll
  for (int nt = 0; nt < 2; ++nt)
#pragma unroll
    for (int r = 0; r < 4; ++r) cst[nt][r] = 0.0f;

#pragma unroll
  for (int t = 0; t < T_; ++t) {
    const int rb = t & 1, wb = rb ^ 1;
    // stage x_{t+1} into the write buffer (read next step)
    if (t + 1 < T_) {
      unsigned p = xpk[(t + 1) >> 1];
      short xv = (short)(((t + 1) & 1) ? (p >> 16) : p);
      hbuf[wb * HBUF + xseq * LDA + 64 + xc] = xv;
    }
#pragma unroll
    for (int nt = 0; nt < 2; ++nt) {
      const int srow = nt * 16 + m16;
      const short* base = &hbuf[rb * HBUF + srow * LDA];
      short8 b0 = *(const short8*)(base + q * 8);
      short8 b1 = *(const short8*)(base + 32 + q * 8);
      short8 b2 = *(const short8*)(base + 64 + q * 8);  // x|bias|pad (overrun OK)
      floatx4 gi = __builtin_amdgcn_mfma_f32_16x16x32_bf16(wA[0][0], b0, zacc, 0, 0, 0);
      floatx4 gf = __builtin_amdgcn_mfma_f32_16x16x32_bf16(wA[1][0], b0, zacc, 0, 0, 0);
      floatx4 gg = __builtin_amdgcn_mfma_f32_16x16x32_bf16(wA[2][0], b0, zacc, 0, 0, 0);
      floatx4 go = __builtin_amdgcn_mfma_f32_16x16x32_bf16(wA[3][0], b0, zacc, 0, 0, 0);
      gi = __builtin_amdgcn_mfma_f32_16x16x32_bf16(wA[0][1], b1, gi, 0, 0, 0);
      gf = __builtin_amdgcn_mfma_f32_16x16x32_bf16(wA[1][1], b1, gf, 0, 0, 0);
      gg = __builtin_amdgcn_mfma_f32_16x16x32_bf16(wA[2][1], b1, gg, 0, 0, 0);
      go = __builtin_amdgcn_mfma_f32_16x16x32_bf16(wA[3][1], b1, go, 0, 0, 0);
      gi = __builtin_amdgcn_mfma_f32_16x16x32_bf16(wA[0][2], b2, gi, 0, 0, 0);
      gf = __builtin_amdgcn_mfma_f32_16x16x32_bf16(wA[1][2], b2, gf, 0, 0, 0);
      gg = __builtin_amdgcn_mfma_f32_16x16x32_bf16(wA[2][2], b2, gg, 0, 0, 0);
      go = __builtin_amdgcn_mfma_f32_16x16x32_bf16(wA[3][2], b2, go, 0, 0, 0);
      float hv[4];
#pragma unroll
      for (int r = 0; r < 4; ++r) {
        float di = 1.0f + __builtin_amdgcn_exp2f(gi[r]);
        float df = 1.0f + __builtin_amdgcn_exp2f(gf[r]);
        float dg = 1.0f + __builtin_amdgcn_exp2f(gg[r]);
        float dq = 1.0f + __builtin_amdgcn_exp2f(go[r]);
        float pa = di * df, pb = dg * dq;
        float rp = __builtin_amdgcn_rcpf(pa * pb);
        float iv = rp * df * pb;                      // sigma(i)
        float fv = rp * di * pb;                      // sigma(f)
        float t1 = rp * pa;
        float gv = fmaf(-2.0f, t1 * dq, 1.0f);        // tanh(g)
        float ov = t1 * dg;                           // sigma(o)
        float cc = fmaf(fv, cst[nt][r], iv * gv);
        cst[nt][r] = cc;
        float dt = 1.0f + __builtin_amdgcn_exp2f(cc * TLOG2E);
        float tc = fmaf(-2.0f, __builtin_amdgcn_rcpf(dt), 1.0f);
        hv[r] = ov * tc;
      }
      unsigned long long pk =
          (unsigned long long)pk_bf16(hv[0], hv[1]) |
          ((unsigned long long)pk_bf16(hv[2], hv[3]) << 32);
      *(unsigned long long*)&hbuf[wb * HBUF + srow * LDA + wave * 16 + q * 4] = pk;
    }
    __syncthreads();
  }

  // ---- final FC: y = h_T @ W_fc^T + b_fc; h_T in buffer 0 ----
  if (wave < 2) {
    short8 f0, f1;
    short8 z = {0, 0, 0, 0, 0, 0, 0, 0};
    if (m16 < 8) {
      const float* wr = W_fc + m16 * 64;
      f0 = load_w8s(wr + q * 8, 1.0f);
      f1 = load_w8s(wr + 32 + q * 8, 1.0f);
    } else {
      f0 = z;
      f1 = z;
    }
    const int srow = wave * 16 + m16;
    short8 h0 = *(const short8*)&hbuf[srow * LDA + q * 8];
    short8 h1 = *(const short8*)&hbuf[srow * LDA + 32 + q * 8];
    floatx4 acc = __builtin_amdgcn_mfma_f32_16x16x32_bf16(f0, h0, zacc, 0, 0, 0);
    acc = __builtin_amdgcn_mfma_f32_16x16x32_bf16(f1, h1, acc, 0, 0, 0);
    if (q < 2) {
      const int orow = blk * MSEQ + srow;
#pragma unroll
      for (int r = 0; r < 4; ++r)
        out[orow * 8 + q * 4 + r] = acc[r] + b_fc[q * 4 + r];
    }
  }
}

extern "C" void kernel_launch(void* const* d_in, const int* in_sizes, int n_in,
                              void* d_out, int out_size, void* d_ws,
                              size_t ws_size, hipStream_t stream) {
  const float* x    = (const float*)d_in[0];
  const float* W_ih = (const float*)d_in[1];
  const float* W_hh = (const float*)d_in[2];
  const float* b_ih = (const float*)d_in[3];
  const float* b_hh = (const float*)d_in[4];
  const float* W_fc = (const float*)d_in[5];
  const float* b_fc = (const float*)d_in[6];
  float* out = (float*)d_out;
  hipLaunchKernelGGL(lstm_kernel, dim3(NBLK), dim3(256), 0, stream,
                     x, W_ih, W_hh, b_ih, b_hh, W_fc, b_fc, out);
}

// Round 5
// 173.072 us; speedup vs baseline: 1.0928x; 1.0928x over previous
//
#include <hip/hip_runtime.h>

#define T_ 12
#define N_ 1370
#define MSEQ 32        // sequences per block
#define LDA 88         // hbuf row stride in shorts (176B): 2-way banks on b128
#define HBUF (MSEQ * LDA)
#define NBLK 2740      // 87680 / 32

typedef __attribute__((ext_vector_type(8))) short short8;
typedef __attribute__((ext_vector_type(4))) float floatx4;

#define NLOG2E -1.4426950408889634f
#define TLOG2E 2.8853900817779268f

__device__ __forceinline__ short f2bf(float x) {
  unsigned u = __builtin_bit_cast(unsigned, x);
  u = (u + 0x7fffu + ((u >> 16) & 1u)) >> 16;
  return (short)u;
}
__device__ __forceinline__ unsigned pk_bf16(float a, float b) {
  unsigned r;
  asm("v_cvt_pk_bf16_f32 %0, %1, %2" : "=v"(r) : "v"(a), "v"(b));
  return r;
}
__device__ __forceinline__ short8 load_w8s(const float* __restrict__ p, float s) {
  short8 r;
#pragma unroll
  for (int j = 0; j < 8; ++j) r[j] = f2bf(p[j] * s);
  return r;
}

// Block = 32 seqs, 4 waves, swapped-operand MFMA: A = weights (m = gate row),
// B = hbuf row [h(0..63) | x_t(64..71) | 1.0(72) | pad(73..87)] (n = seq).
// Chunk2 A rows: q=0 -> W_ih (k=64..71), q=1 j=0 -> scaled bias (k=72),
// all other rows ZERO -> pad/overrun B values multiplied by zero = harmless.
// x held in registers (12 bf16 in 6 VGPRs/thread), dropped into the write
// buffer's x columns each step (one ds_write_b16).
// D layout: col=lane&15 = seq, row=q*4+r = unit -> i/f/g/o of a cell share
// reg index r; c stays fp32 in registers; h writeback = one ds_write_b64.
// Activation scaling pre-folded: i,f,o rows by -log2e (sigma = 1/(1+2^y)),
// g rows by 2*log2e (tanh = 1 - 2/(1+2^y)); one v_rcp serves all 4 gates.
// launch_bounds (256,4): (256,5) spilled to scratch in R4 (WRITE_SIZE 98MB).
__global__ void __launch_bounds__(256, 4) lstm_kernel(
    const float* __restrict__ x, const float* __restrict__ W_ih,
    const float* __restrict__ W_hh, const float* __restrict__ b_ih,
    const float* __restrict__ b_hh, const float* __restrict__ W_fc,
    const float* __restrict__ b_fc, float* __restrict__ out) {
  __shared__ short hbuf[2 * HBUF + 8];  // +8: q=3 chunk2 overrun pad

  const int tid = threadIdx.x;
  const int wave = tid >> 6;
  const int lane = tid & 63;
  const int m16 = lane & 15;
  const int q = lane >> 4;
  const int blk = blockIdx.x;

  // ---- x -> registers: thread (xseq, xc) holds x[xseq][t][xc], t=0..11 ----
  const int xseq = tid >> 3, xc = tid & 7;
  unsigned xpk[6];
  {
    const int s0 = blk * MSEQ + xseq;
    const int bidx = s0 / N_;
    const int nidx = s0 - bidx * N_;
    const float* xp = x + ((size_t)(bidx * T_) * N_ + nidx) * 8 + xc;
    float xv[T_];
#pragma unroll
    for (int t = 0; t < T_; ++t) xv[t] = xp[(size_t)t * (N_ * 8)];
#pragma unroll
    for (int i = 0; i < 6; ++i) xpk[i] = pk_bf16(xv[2 * i], xv[2 * i + 1]);
  }

  // ---- A-operand weight fragments: lane row = gate unit wave*16+m16 ----
  const int urow = wave * 16 + m16;
  short8 wA[4][3];
#pragma unroll
  for (int g = 0; g < 4; ++g) {
    const float sg = (g == 2) ? TLOG2E : NLOG2E;
    const int grow = g * 64 + urow;
    const float* wr = W_hh + grow * 64;
    wA[g][0] = load_w8s(wr + q * 8, sg);
    wA[g][1] = load_w8s(wr + 32 + q * 8, sg);
    short8 z = {0, 0, 0, 0, 0, 0, 0, 0};
    if (q == 0) {
      wA[g][2] = load_w8s(W_ih + grow * 8, sg);      // k = 64..71: x cols
    } else if (q == 1) {
      z[0] = f2bf(sg * (b_ih[grow] + b_hh[grow]));   // k = 72: bias col
      wA[g][2] = z;
    } else {
      wA[g][2] = z;                                  // k = 80..95 dead
    }
  }

  // ---- zero LDS (h0 = 0), then bias columns + x_0 ----
  {
    int* hp = (int*)hbuf;
#pragma unroll
    for (int i = tid; i < (2 * HBUF + 8) / 2; i += 256) hp[i] = 0;
  }
  __syncthreads();
  if (tid < 2 * MSEQ)
    hbuf[(tid >> 5) * HBUF + (tid & 31) * LDA + 72] = (short)0x3F80;  // 1.0
  hbuf[xseq * LDA + 64 + xc] = (short)xpk[0];  // x_0 into buffer 0
  __syncthreads();

  const floatx4 zacc = {0.0f, 0.0f, 0.0f, 0.0f};
  float cst[2][4];
#pragma unroll
  for (int nt = 0; nt < 2; ++nt)
#pragma unroll
    for (int r = 0; r < 4; ++r) cst[nt][r] = 0.0f;

#pragma unroll
  for (int t = 0; t < T_; ++t) {
    const int rb = t & 1, wb = rb ^ 1;
    // stage x_{t+1} into the write buffer (read next step)
    if (t + 1 < T_) {
      unsigned p = xpk[(t + 1) >> 1];
      short xv = (short)(((t + 1) & 1) ? (p >> 16) : p);
      hbuf[wb * HBUF + xseq * LDA + 64 + xc] = xv;
    }
#pragma unroll
    for (int nt = 0; nt < 2; ++nt) {
      const int srow = nt * 16 + m16;
      const short* base = &hbuf[rb * HBUF + srow * LDA];
      short8 b0 = *(const short8*)(base + q * 8);
      short8 b1 = *(const short8*)(base + 32 + q * 8);
      short8 b2 = *(const short8*)(base + 64 + q * 8);  // x|bias|pad (overrun OK)
      floatx4 gi = __builtin_amdgcn_mfma_f32_16x16x32_bf16(wA[0][0], b0, zacc, 0, 0, 0);
      floatx4 gf = __builtin_amdgcn_mfma_f32_16x16x32_bf16(wA[1][0], b0, zacc, 0, 0, 0);
      floatx4 gg = __builtin_amdgcn_mfma_f32_16x16x32_bf16(wA[2][0], b0, zacc, 0, 0, 0);
      floatx4 go = __builtin_amdgcn_mfma_f32_16x16x32_bf16(wA[3][0], b0, zacc, 0, 0, 0);
      gi = __builtin_amdgcn_mfma_f32_16x16x32_bf16(wA[0][1], b1, gi, 0, 0, 0);
      gf = __builtin_amdgcn_mfma_f32_16x16x32_bf16(wA[1][1], b1, gf, 0, 0, 0);
      gg = __builtin_amdgcn_mfma_f32_16x16x32_bf16(wA[2][1], b1, gg, 0, 0, 0);
      go = __builtin_amdgcn_mfma_f32_16x16x32_bf16(wA[3][1], b1, go, 0, 0, 0);
      gi = __builtin_amdgcn_mfma_f32_16x16x32_bf16(wA[0][2], b2, gi, 0, 0, 0);
      gf = __builtin_amdgcn_mfma_f32_16x16x32_bf16(wA[1][2], b2, gf, 0, 0, 0);
      gg = __builtin_amdgcn_mfma_f32_16x16x32_bf16(wA[2][2], b2, gg, 0, 0, 0);
      go = __builtin_amdgcn_mfma_f32_16x16x32_bf16(wA[3][2], b2, go, 0, 0, 0);
      float hv[4];
#pragma unroll
      for (int r = 0; r < 4; ++r) {
        float di = 1.0f + __builtin_amdgcn_exp2f(gi[r]);
        float df = 1.0f + __builtin_amdgcn_exp2f(gf[r]);
        float dg = 1.0f + __builtin_amdgcn_exp2f(gg[r]);
        float dq = 1.0f + __builtin_amdgcn_exp2f(go[r]);
        float pa = di * df, pb = dg * dq;
        float rp = __builtin_amdgcn_rcpf(pa * pb);
        float iv = rp * df * pb;                      // sigma(i)
        float fv = rp * di * pb;                      // sigma(f)
        float t1 = rp * pa;
        float gv = fmaf(-2.0f, t1 * dq, 1.0f);        // tanh(g)
        float ov = t1 * dg;                           // sigma(o)
        float cc = fmaf(fv, cst[nt][r], iv * gv);
        cst[nt][r] = cc;
        float dt = 1.0f + __builtin_amdgcn_exp2f(cc * TLOG2E);
        float tc = fmaf(-2.0f, __builtin_amdgcn_rcpf(dt), 1.0f);
        hv[r] = ov * tc;
      }
      unsigned long long pk =
          (unsigned long long)pk_bf16(hv[0], hv[1]) |
          ((unsigned long long)pk_bf16(hv[2], hv[3]) << 32);
      *(unsigned long long*)&hbuf[wb * HBUF + srow * LDA + wave * 16 + q * 4] = pk;
    }
    __syncthreads();
  }

  // ---- final FC: y = h_T @ W_fc^T + b_fc; h_T in buffer 0 ----
  if (wave < 2) {
    short8 f0, f1;
    short8 z = {0, 0, 0, 0, 0, 0, 0, 0};
    if (m16 < 8) {
      const float* wr = W_fc + m16 * 64;
      f0 = load_w8s(wr + q * 8, 1.0f);
      f1 = load_w8s(wr + 32 + q * 8, 1.0f);
    } else {
      f0 = z;
      f1 = z;
    }
    const int srow = wave * 16 + m16;
    short8 h0 = *(const short8*)&hbuf[srow * LDA + q * 8];
    short8 h1 = *(const short8*)&hbuf[srow * LDA + 32 + q * 8];
    floatx4 acc = __builtin_amdgcn_mfma_f32_16x16x32_bf16(f0, h0, zacc, 0, 0, 0);
    acc = __builtin_amdgcn_mfma_f32_16x16x32_bf16(f1, h1, acc, 0, 0, 0);
    if (q < 2) {
      const int orow = blk * MSEQ + srow;
#pragma unroll
      for (int r = 0; r < 4; ++r)
        out[orow * 8 + q * 4 + r] = acc[r] + b_fc[q * 4 + r];
    }
  }
}

extern "C" void kernel_launch(void* const* d_in, const int* in_sizes, int n_in,
                              void* d_out, int out_size, void* d_ws,
                              size_t ws_size, hipStream_t stream) {
  const float* x    = (const float*)d_in[0];
  const float* W_ih = (const float*)d_in[1];
  const float* W_hh = (const float*)d_in[2];
  const float* b_ih = (const float*)d_in[3];
  const float* b_hh = (const float*)d_in[4];
  const float* W_fc = (const float*)d_in[5];
  const float* b_fc = (const float*)d_in[6];
  float* out = (float*)d_out;
  hipLaunchKernelGGL(lstm_kernel, dim3(NBLK), dim3(256), 0, stream,
                     x, W_ih, W_hh, b_ih, b_hh, W_fc, b_fc, out);
}